// Round 6
// baseline (193.926 us; speedup 1.0000x reference)
//
#include <hip/hip_runtime.h>

// GraphSage on MI355X — round 6.
//   prep  : feat fp32 -> fb bf16 (GEMM self operand) + f8 fp8 e4m3 (gather source)
//           + w1,w2 -> w1T,w2T bf16 [n][k]
//   k1_agg: agg[N,128] bf16 = mean_d f8[nbr[n][d]].  Loads-first structure: all 16
//           neighbor loads issued before any convert (round-1 profile: VGPR=20 ->
//           only ~4 outstanding loads -> latency-serialized).
//   g1    : h1 = [fb | agg] @ w1T.  256 rows/block, B in LDS, A triple-buffered
//           (prefetch depth 2 covers ~900-cyc HBM latency), macro-expanded (no
//           lambdas/pointer-indexed buffers -> round-5 suspect for spills).
//   g2    : out = [h1[node] | mean h1[nbr]] @ w2T  (fused, 64 rows/block)

#define N_NODES 100000
#define DEG     16
#define FDIM    128
#define HDIM    128
#define B_NODES 8192

typedef __attribute__((ext_vector_type(8))) short bf16x8;
typedef __attribute__((ext_vector_type(8))) unsigned short u16x8;
typedef __attribute__((ext_vector_type(4))) float f32x4;
typedef __attribute__((ext_vector_type(2))) float f32x2;

static __device__ __forceinline__ unsigned short f2bf(float f) {
    union { float f; unsigned u; } v; v.f = f;
    unsigned r = v.u + 0x7fff + ((v.u >> 16) & 1);   // RNE
    return (unsigned short)(r >> 16);
}
static __device__ __forceinline__ float bf2f(unsigned short b) {
    union { unsigned u; float f; } v; v.u = ((unsigned)b) << 16;
    return v.f;
}

// blocks 0..6249: cast feat -> fb (bf16) + f8 (fp8). blocks 6250..6265: w1/w2 transpose.
__global__ __launch_bounds__(256)
void prep(const float* __restrict__ feat, const float* __restrict__ w1,
          const float* __restrict__ w2, unsigned short* __restrict__ fb,
          unsigned char* __restrict__ f8,
          unsigned short* __restrict__ w1T, unsigned short* __restrict__ w2T) {
    if (blockIdx.x < 6250) {
        long e = ((long)blockIdx.x * 256 + threadIdx.x) * 8;   // 6250*256*8 = 12.8M exact
        float4 v0 = *(const float4*)(feat + e);
        float4 v1 = *(const float4*)(feat + e + 4);
        u16x8 ob;
        ob[0] = f2bf(v0.x); ob[1] = f2bf(v0.y); ob[2] = f2bf(v0.z); ob[3] = f2bf(v0.w);
        ob[4] = f2bf(v1.x); ob[5] = f2bf(v1.y); ob[6] = f2bf(v1.z); ob[7] = f2bf(v1.w);
        *(u16x8*)(fb + e) = ob;
        int p0 = 0, p1 = 0;
        p0 = __builtin_amdgcn_cvt_pk_fp8_f32(v0.x, v0.y, p0, false);
        p0 = __builtin_amdgcn_cvt_pk_fp8_f32(v0.z, v0.w, p0, true);
        p1 = __builtin_amdgcn_cvt_pk_fp8_f32(v1.x, v1.y, p1, false);
        p1 = __builtin_amdgcn_cvt_pk_fp8_f32(v1.z, v1.w, p1, true);
        uint2 o8; o8.x = (unsigned)p0; o8.y = (unsigned)p1;
        *(uint2*)(f8 + e) = o8;
    } else {
        int bid = blockIdx.x - 6250;
        const float* w = (bid < 8) ? w1 : w2;
        unsigned short* wT = (bid < 8) ? w1T : w2T;
        int kb = (bid & 7) * 32;
        int n = threadIdx.x & 127, dk = threadIdx.x >> 7;
#pragma unroll
        for (int i = 0; i < 16; ++i) {
            int k = kb + dk * 16 + i;
            wT[n * 256 + k] = f2bf(w[k * 128 + n]);   // read coalesced over n
        }
    }
}

// 16 nodes per 256-thread block; 16 lanes per node, 8 B fp8 per lane per neighbor.
// All 16 loads issued before conversion: maximizes memory-level parallelism.
__global__ __launch_bounds__(256)
void k1_agg(const unsigned char* __restrict__ f8, const int* __restrict__ nbr,
            unsigned short* __restrict__ agg) {
    const int t = threadIdx.x;
    const int node = blockIdx.x * 16 + (t >> 4);      // 6250*16 = 100000 exact
    const int cg = (t & 15) * 8;
    const int* idx = nbr + node * DEG;
    int4 i0 = *(const int4*)(idx);
    int4 i1 = *(const int4*)(idx + 4);
    int4 i2 = *(const int4*)(idx + 8);
    int4 i3 = *(const int4*)(idx + 12);
    int id[16] = {i0.x, i0.y, i0.z, i0.w, i1.x, i1.y, i1.z, i1.w,
                  i2.x, i2.y, i2.z, i2.w, i3.x, i3.y, i3.z, i3.w};
    uint2 v[16];
#pragma unroll
    for (int d = 0; d < DEG; ++d)
        v[d] = *(const uint2*)(f8 + (long)id[d] * FDIM + cg);
    float s[8] = {0.f, 0.f, 0.f, 0.f, 0.f, 0.f, 0.f, 0.f};
#pragma unroll
    for (int d = 0; d < DEG; ++d) {
        f32x2 a0 = __builtin_amdgcn_cvt_pk_f32_fp8((int)v[d].x, false);
        f32x2 a1 = __builtin_amdgcn_cvt_pk_f32_fp8((int)v[d].x, true);
        f32x2 a2 = __builtin_amdgcn_cvt_pk_f32_fp8((int)v[d].y, false);
        f32x2 a3 = __builtin_amdgcn_cvt_pk_f32_fp8((int)v[d].y, true);
        s[0] += a0[0]; s[1] += a0[1]; s[2] += a1[0]; s[3] += a1[1];
        s[4] += a2[0]; s[5] += a2[1]; s[6] += a3[0]; s[7] += a3[1];
    }
    u16x8 o;
#pragma unroll
    for (int j = 0; j < 8; ++j) o[j] = f2bf(s[j] * 0.0625f);
    *(u16x8*)(agg + node * 128 + cg) = o;
}

// Loads one 32-row chunk's A fragments (2 row-tiles x 8 kc) into BUF.
#define LOAD_CHUNK(BUF, CIDX)                                                        \
    do {                                                                             \
        const int r0_ = row0 + (CIDX) * 32;                                          \
        _Pragma("unroll")                                                            \
        for (int mt_ = 0; mt_ < 2; ++mt_) {                                          \
            int grow_ = r0_ + mt_ * 16 + m16;                                        \
            bool ok_ = grow_ < N_NODES;                                              \
            const unsigned short* pf_ = fb + (long)grow_ * 128 + quad * 8;           \
            const unsigned short* pa_ = agg + (long)grow_ * 128 + quad * 8;          \
            bf16x8 z_ = {};                                                          \
            _Pragma("unroll")                                                        \
            for (int kc_ = 0; kc_ < 4; ++kc_)                                        \
                BUF[mt_][kc_] = ok_ ? *(const bf16x8*)(pf_ + kc_ * 32) : z_;         \
            _Pragma("unroll")                                                        \
            for (int kc_ = 0; kc_ < 4; ++kc_)                                        \
                BUF[mt_][4 + kc_] = ok_ ? *(const bf16x8*)(pa_ + kc_ * 32) : z_;     \
        }                                                                            \
    } while (0)

// GEMM: h1 = [fb | agg] @ w1T. 256 rows x 128 cols per block; 4 waves, each a 32-col
// slice. B staged in LDS once; A triple-buffered with prefetch depth 2.
__global__ __launch_bounds__(256, 2)
void g1(const unsigned short* __restrict__ fb, const unsigned short* __restrict__ agg,
        const unsigned short* __restrict__ w1T, unsigned short* __restrict__ h1) {
    __shared__ unsigned short W[128][264];   // dword stride 132 -> uniform 8-bank spread
    const int t = threadIdx.x, wave = t >> 6, lane = t & 63;
    const int m16 = lane & 15, quad = lane >> 4;
    const int row0 = blockIdx.x * 256;
    const int n0 = wave * 32;

    // Stage w1T (128x256 bf16 = 64 KB) into LDS. 256 thr x 16 iters x 16 B.
#pragma unroll
    for (int i = 0; i < 16; ++i) {
        int e = i * 2048 + t * 8;
        int n = e >> 8, k = e & 255;
        *(u16x8*)(&W[n][k]) = *(const u16x8*)(w1T + e);
    }
    __syncthreads();

    bf16x8 A0[2][8], A1[2][8], A2[2][8];
    LOAD_CHUNK(A0, 0);
    LOAD_CHUNK(A1, 1);

#pragma unroll
    for (int c = 0; c < 8; ++c) {
        // Prefetch chunk c+2 into the buffer freed two iterations ago.
        if (c < 6) {
            if ((c % 3) == 0)      LOAD_CHUNK(A2, c + 2);
            else if ((c % 3) == 1) LOAD_CHUNK(A0, c + 2);
            else                   LOAD_CHUNK(A1, c + 2);
        }
        f32x4 acc[2][2] = {};
#pragma unroll
        for (int kc = 0; kc < 8; ++kc) {
            bf16x8 b0 = *(const bf16x8*)(&W[n0 + m16][kc * 32 + quad * 8]);
            bf16x8 b1 = *(const bf16x8*)(&W[n0 + 16 + m16][kc * 32 + quad * 8]);
            bf16x8 a0, a1;
            if ((c % 3) == 0)      { a0 = A0[0][kc]; a1 = A0[1][kc]; }
            else if ((c % 3) == 1) { a0 = A1[0][kc]; a1 = A1[1][kc]; }
            else                   { a0 = A2[0][kc]; a1 = A2[1][kc]; }
            acc[0][0] = __builtin_amdgcn_mfma_f32_16x16x32_bf16(a0, b0, acc[0][0], 0, 0, 0);
            acc[1][0] = __builtin_amdgcn_mfma_f32_16x16x32_bf16(a1, b0, acc[1][0], 0, 0, 0);
            acc[0][1] = __builtin_amdgcn_mfma_f32_16x16x32_bf16(a0, b1, acc[0][1], 0, 0, 0);
            acc[1][1] = __builtin_amdgcn_mfma_f32_16x16x32_bf16(a1, b1, acc[1][1], 0, 0, 0);
        }
        // C layout: row = quad*4 + reg, col within wave slice = nt*16 + m16
        const int r0 = row0 + c * 32;
#pragma unroll
        for (int mt = 0; mt < 2; ++mt)
#pragma unroll
            for (int reg = 0; reg < 4; ++reg) {
                int grow = r0 + mt * 16 + quad * 4 + reg;
                if (grow >= N_NODES) continue;
#pragma unroll
                for (int nt = 0; nt < 2; ++nt)
                    h1[grow * HDIM + n0 + nt * 16 + m16] = f2bf(acc[mt][nt][reg]);
            }
    }
}

// Layer 2 fused: 64 batch rows per 256-thread block. 128 blocks exact.
__global__ __launch_bounds__(256)
void g2_fused(const unsigned short* __restrict__ h1, const unsigned short* __restrict__ w2T,
              const int* __restrict__ nbr, const int* __restrict__ nodes,
              float* __restrict__ out) {
    __shared__ unsigned short X2[64][264];
    const int t = threadIdx.x, wave = t >> 6, lane = t & 63;
    const int m16 = lane & 15, quad = lane >> 4;
    const int b0 = blockIdx.x * 64;
    const int colb = m16 * 8;

    for (int g = 0; g < 4; ++g) {
        int Ln = wave * 16 + g * 4 + quad;
        int node = nodes[b0 + Ln];
        *(u16x8*)(&X2[Ln][colb]) = *(const u16x8*)(h1 + node * HDIM + colb);
        const int* idx = nbr + node * DEG;
        float s[8] = {0.f, 0.f, 0.f, 0.f, 0.f, 0.f, 0.f, 0.f};
#pragma unroll
        for (int d = 0; d < DEG; ++d) {
            int nb = idx[d];
            u16x8 v = *(const u16x8*)(h1 + nb * HDIM + colb);
#pragma unroll
            for (int j = 0; j < 8; ++j) s[j] += bf2f(v[j]);
        }
        u16x8 o;
#pragma unroll
        for (int j = 0; j < 8; ++j) o[j] = f2bf(s[j] * 0.0625f);
        *(u16x8*)(&X2[Ln][128 + colb]) = o;
    }
    __syncthreads();

    f32x4 acc[8] = {};
#pragma unroll
    for (int kc = 0; kc < 8; ++kc) {
        bf16x8 a = *(const bf16x8*)(&X2[wave * 16 + m16][kc * 32 + quad * 8]);
#pragma unroll
        for (int nt = 0; nt < 8; ++nt) {
            bf16x8 b = *(const bf16x8*)(w2T + (nt * 16 + m16) * 256 + kc * 32 + quad * 8);
            acc[nt] = __builtin_amdgcn_mfma_f32_16x16x32_bf16(a, b, acc[nt], 0, 0, 0);
        }
    }

#pragma unroll
    for (int nt = 0; nt < 8; ++nt)
#pragma unroll
        for (int reg = 0; reg < 4; ++reg) {
            int row = b0 + wave * 16 + quad * 4 + reg;
            out[row * 128 + nt * 16 + m16] = acc[nt][reg];
        }
}

extern "C" void kernel_launch(void* const* d_in, const int* in_sizes, int n_in,
                              void* d_out, int out_size, void* d_ws, size_t ws_size,
                              hipStream_t stream) {
    const float* feat  = (const float*)d_in[0];
    const float* w1    = (const float*)d_in[1];
    const float* w2    = (const float*)d_in[2];
    const int*   nbr   = (const int*)d_in[3];
    const int*   nodes = (const int*)d_in[4];
    float* out = (float*)d_out;

    char* ws = (char*)d_ws;
    unsigned short* fb  = (unsigned short*)ws;                       // N*128 bf16 = 25.6 MB
    unsigned char*  f8  = (unsigned char*)(ws + 25600000);           // N*128 fp8  = 12.8 MB
    unsigned short* agg = (unsigned short*)(ws + 38400000);          // N*128 bf16 = 25.6 MB
    unsigned short* h1  = (unsigned short*)(ws + 64000000);          // N*128 bf16 = 25.6 MB
    unsigned short* w1T = (unsigned short*)(ws + 89600000);          // 64 KB
    unsigned short* w2T = (unsigned short*)(ws + 89665536);          // 64 KB

    prep<<<6266, 256, 0, stream>>>(feat, w1, w2, fb, f8, w1T, w2T);
    k1_agg<<<6250, 256, 0, stream>>>(f8, nbr, agg);
    g1<<<(N_NODES + 255) / 256, 256, 0, stream>>>(fb, agg, w1T, h1);
    g2_fused<<<B_NODES / 64, 256, 0, stream>>>(h1, w2T, nbr, nodes, out);
}

// Round 7
// 173.149 us; speedup vs baseline: 1.1200x; 1.1200x over previous
//
#include <hip/hip_runtime.h>

// GraphSage on MI355X — round 7.
//   prep  : feat fp32 -> fb bf16 (GEMM self operand) + f8s fp8 e4m3 column-sliced
//           [4 slices][N][32B] (each 3.2 MB slice fits one XCD's 4 MB L2)
//           + w1,w2 -> w1T,w2T bf16 [n][k]
//   k1_agg: XCD-sliced gather: blockIdx%8 pins slice -> XCD L2 stays hot.
//           agg[N, s*32..] = mean_d f8s[s][nbr[n][d]].  16 loads up-front, VGPR ~70.
//   g1    : h1 = [fb | agg] @ w1T.  m97-style: BK=32 double-buffered LDS staging via
//           global_load_lds (async, no VGPR arrays -> no spills), 16 MFMA per barrier.
//   g2    : out = [h1[node] | mean h1[nbr]] @ w2T  (fused, 64 rows/block)

#define N_NODES 100000
#define DEG     16
#define FDIM    128
#define HDIM    128
#define B_NODES 8192

typedef __attribute__((ext_vector_type(8))) short bf16x8;
typedef __attribute__((ext_vector_type(8))) unsigned short u16x8;
typedef __attribute__((ext_vector_type(4))) float f32x4;
typedef __attribute__((ext_vector_type(2))) float f32x2;

static __device__ __forceinline__ unsigned short f2bf(float f) {
    union { float f; unsigned u; } v; v.f = f;
    unsigned r = v.u + 0x7fff + ((v.u >> 16) & 1);   // RNE
    return (unsigned short)(r >> 16);
}
static __device__ __forceinline__ float bf2f(unsigned short b) {
    union { unsigned u; float f; } v; v.u = ((unsigned)b) << 16;
    return v.f;
}

// blocks 0..6249: cast feat -> fb (bf16) + f8s (fp8, column-sliced).
// blocks 6250..6265: w1/w2 transpose.
__global__ __launch_bounds__(256)
void prep(const float* __restrict__ feat, const float* __restrict__ w1,
          const float* __restrict__ w2, unsigned short* __restrict__ fb,
          unsigned char* __restrict__ f8s,
          unsigned short* __restrict__ w1T, unsigned short* __restrict__ w2T) {
    if (blockIdx.x < 6250) {
        long e = ((long)blockIdx.x * 256 + threadIdx.x) * 8;   // 6250*256*8 = 12.8M exact
        float4 v0 = *(const float4*)(feat + e);
        float4 v1 = *(const float4*)(feat + e + 4);
        u16x8 ob;
        ob[0] = f2bf(v0.x); ob[1] = f2bf(v0.y); ob[2] = f2bf(v0.z); ob[3] = f2bf(v0.w);
        ob[4] = f2bf(v1.x); ob[5] = f2bf(v1.y); ob[6] = f2bf(v1.z); ob[7] = f2bf(v1.w);
        *(u16x8*)(fb + e) = ob;
        int p0 = 0, p1 = 0;
        p0 = __builtin_amdgcn_cvt_pk_fp8_f32(v0.x, v0.y, p0, false);
        p0 = __builtin_amdgcn_cvt_pk_fp8_f32(v0.z, v0.w, p0, true);
        p1 = __builtin_amdgcn_cvt_pk_fp8_f32(v1.x, v1.y, p1, false);
        p1 = __builtin_amdgcn_cvt_pk_fp8_f32(v1.z, v1.w, p1, true);
        // column-sliced dest: slice = col/32; f8s[slice][node][col%32]
        int node = (int)(e >> 7), col = (int)(e & 127);
        int slice = col >> 5;
        unsigned char* dst = f8s + (long)slice * (N_NODES * 32) + (long)node * 32 + (col & 31);
        uint2 o8; o8.x = (unsigned)p0; o8.y = (unsigned)p1;
        *(uint2*)dst = o8;
    } else {
        int bid = blockIdx.x - 6250;
        const float* w = (bid < 8) ? w1 : w2;
        unsigned short* wT = (bid < 8) ? w1T : w2T;
        int kb = (bid & 7) * 32;
        int n = threadIdx.x & 127, dk = threadIdx.x >> 7;
#pragma unroll
        for (int i = 0; i < 16; ++i) {
            int k = kb + dk * 16 + i;
            wT[n * 256 + k] = f2bf(w[k * 128 + n]);   // read coalesced over n
        }
    }
}

// XCD-sliced gather. Block b: slice s = (b%8)/2 (pinned to an XCD pair if dispatch is
// round-robin %8), node chunk = (b/8)*2 + (b%8)%2, 64 nodes/chunk, 4 threads/node.
__global__ __launch_bounds__(256)
void k1_agg(const unsigned char* __restrict__ f8s, const int* __restrict__ nbr,
            unsigned short* __restrict__ agg) {
    const int t = threadIdx.x, b = blockIdx.x;
    const int s = (b & 7) >> 1;
    const int chunk = ((b >> 3) << 1) + (b & 1);
    const int node = chunk * 64 + (t >> 2);
    if (node >= N_NODES) return;
    const int q = t & 3;
    const unsigned char* base = f8s + (long)s * (N_NODES * 32) + q * 8;
    const int* idx = nbr + node * DEG;
    int4 i0 = *(const int4*)(idx);
    int4 i1 = *(const int4*)(idx + 4);
    int4 i2 = *(const int4*)(idx + 8);
    int4 i3 = *(const int4*)(idx + 12);
    int id[16] = {i0.x, i0.y, i0.z, i0.w, i1.x, i1.y, i1.z, i1.w,
                  i2.x, i2.y, i2.z, i2.w, i3.x, i3.y, i3.z, i3.w};
    uint2 v[16];
#pragma unroll
    for (int d = 0; d < DEG; ++d)
        v[d] = *(const uint2*)(base + (long)id[d] * 32);
    float sm[8] = {0.f, 0.f, 0.f, 0.f, 0.f, 0.f, 0.f, 0.f};
#pragma unroll
    for (int d = 0; d < DEG; ++d) {
        f32x2 a0 = __builtin_amdgcn_cvt_pk_f32_fp8((int)v[d].x, false);
        f32x2 a1 = __builtin_amdgcn_cvt_pk_f32_fp8((int)v[d].x, true);
        f32x2 a2 = __builtin_amdgcn_cvt_pk_f32_fp8((int)v[d].y, false);
        f32x2 a3 = __builtin_amdgcn_cvt_pk_f32_fp8((int)v[d].y, true);
        sm[0] += a0[0]; sm[1] += a0[1]; sm[2] += a1[0]; sm[3] += a1[1];
        sm[4] += a2[0]; sm[5] += a2[1]; sm[6] += a3[0]; sm[7] += a3[1];
    }
    u16x8 o;
#pragma unroll
    for (int j = 0; j < 8; ++j) o[j] = f2bf(sm[j] * 0.0625f);
    *(u16x8*)(agg + (long)node * 128 + s * 32 + q * 8) = o;
}

// Stage one K-chunk (A rows + W rows, 8 KB each) into LDS buf via global_load_lds.
// Chunk layout [row][32] shorts: 64 B row stride -> 2-way bank alias (free).
// Dest = wave-uniform base + lane*16 B (required by global_load_lds).
#define STAGE(KC, BUF)                                                                        \
    do {                                                                                      \
        const unsigned short* s0_ = ((KC) < 4) ? (fb + (KC) * 32) : (agg + ((KC) - 4) * 32);  \
        _Pragma("unroll")                                                                     \
        for (int j_ = 0; j_ < 2; ++j_) {                                                      \
            long grow_ = row0 + (t >> 2) + j_ * 64;                                           \
            const unsigned short* ga_ = s0_ + grow_ * 128 + (t & 3) * 8;                      \
            __builtin_amdgcn_global_load_lds(                                                 \
                (const __attribute__((address_space(1))) unsigned int*)ga_,                   \
                (__attribute__((address_space(3))) unsigned int*)                             \
                    (&AsS[(BUF) * 4096 + wave * 512 + j_ * 2048 + lane * 8]), 16, 0, 0);      \
            const unsigned short* gw_ = w1T + ((t >> 2) + j_ * 64) * 256 + (KC) * 32 + (t & 3) * 8; \
            __builtin_amdgcn_global_load_lds(                                                 \
                (const __attribute__((address_space(1))) unsigned int*)gw_,                   \
                (__attribute__((address_space(3))) unsigned int*)                             \
                    (&WsS[(BUF) * 4096 + wave * 512 + j_ * 2048 + lane * 8]), 16, 0, 0);      \
        }                                                                                     \
    } while (0)

// GEMM: h1[N,128] = [fb | agg] @ w1T. 128 rows/block, BK=32, double-buffered async LDS.
// Rows >= N stage garbage (still inside ws) and are simply not stored.
__global__ __launch_bounds__(256, 2)
void g1(const unsigned short* __restrict__ fb, const unsigned short* __restrict__ agg,
        const unsigned short* __restrict__ w1T, unsigned short* __restrict__ h1) {
    __shared__ unsigned short AsS[2 * 4096];   // 2 x 128 rows x 32 k (8 KB each)
    __shared__ unsigned short WsS[2 * 4096];
    const int t = threadIdx.x, wave = t >> 6, lane = t & 63;
    const int m16 = lane & 15, quad = lane >> 4;
    const long row0 = (long)blockIdx.x * 128;

    f32x4 acc[2][8] = {};
    STAGE(0, 0);
#pragma unroll
    for (int kc = 0; kc < 8; ++kc) {
        __syncthreads();                       // drains vmcnt -> staging of kc complete
        if (kc < 7) {
            switch (kc + 1) {                  // constant-fold each STAGE
                case 1: STAGE(1, 1); break;
                case 2: STAGE(2, 0); break;
                case 3: STAGE(3, 1); break;
                case 4: STAGE(4, 0); break;
                case 5: STAGE(5, 1); break;
                case 6: STAGE(6, 0); break;
                case 7: STAGE(7, 1); break;
            }
        }
        const unsigned short* Ab = &AsS[(kc & 1) * 4096];
        const unsigned short* Wb = &WsS[(kc & 1) * 4096];
        bf16x8 a0 = *(const bf16x8*)(Ab + (wave * 32 + m16) * 32 + quad * 8);
        bf16x8 a1 = *(const bf16x8*)(Ab + (wave * 32 + 16 + m16) * 32 + quad * 8);
#pragma unroll
        for (int nt = 0; nt < 8; ++nt) {
            bf16x8 bv = *(const bf16x8*)(Wb + (nt * 16 + m16) * 32 + quad * 8);
            acc[0][nt] = __builtin_amdgcn_mfma_f32_16x16x32_bf16(a0, bv, acc[0][nt], 0, 0, 0);
            acc[1][nt] = __builtin_amdgcn_mfma_f32_16x16x32_bf16(a1, bv, acc[1][nt], 0, 0, 0);
        }
    }

    // C layout: row = quad*4 + reg, col = nt*16 + m16
#pragma unroll
    for (int mt = 0; mt < 2; ++mt)
#pragma unroll
        for (int reg = 0; reg < 4; ++reg) {
            long grow = row0 + wave * 32 + mt * 16 + quad * 4 + reg;
            if (grow >= N_NODES) continue;
#pragma unroll
            for (int nt = 0; nt < 8; ++nt)
                h1[grow * HDIM + nt * 16 + m16] = f2bf(acc[mt][nt][reg]);
        }
}

// Layer 2 fused: 64 batch rows per 256-thread block. 128 blocks exact.
__global__ __launch_bounds__(256)
void g2_fused(const unsigned short* __restrict__ h1, const unsigned short* __restrict__ w2T,
              const int* __restrict__ nbr, const int* __restrict__ nodes,
              float* __restrict__ out) {
    __shared__ unsigned short X2[64][264];
    const int t = threadIdx.x, wave = t >> 6, lane = t & 63;
    const int m16 = lane & 15, quad = lane >> 4;
    const int b0 = blockIdx.x * 64;
    const int colb = m16 * 8;

    for (int g = 0; g < 4; ++g) {
        int Ln = wave * 16 + g * 4 + quad;
        int node = nodes[b0 + Ln];
        *(u16x8*)(&X2[Ln][colb]) = *(const u16x8*)(h1 + node * HDIM + colb);
        const int* idx = nbr + node * DEG;
        float s[8] = {0.f, 0.f, 0.f, 0.f, 0.f, 0.f, 0.f, 0.f};
#pragma unroll
        for (int d = 0; d < DEG; ++d) {
            int nb = idx[d];
            u16x8 v = *(const u16x8*)(h1 + nb * HDIM + colb);
#pragma unroll
            for (int j = 0; j < 8; ++j) s[j] += bf2f(v[j]);
        }
        u16x8 o;
#pragma unroll
        for (int j = 0; j < 8; ++j) o[j] = f2bf(s[j] * 0.0625f);
        *(u16x8*)(&X2[Ln][128 + colb]) = o;
    }
    __syncthreads();

    f32x4 acc[8] = {};
#pragma unroll
    for (int kc = 0; kc < 8; ++kc) {
        bf16x8 a = *(const bf16x8*)(&X2[wave * 16 + m16][kc * 32 + quad * 8]);
#pragma unroll
        for (int nt = 0; nt < 8; ++nt) {
            bf16x8 b = *(const bf16x8*)(w2T + (nt * 16 + m16) * 256 + kc * 32 + quad * 8);
            acc[nt] = __builtin_amdgcn_mfma_f32_16x16x32_bf16(a, b, acc[nt], 0, 0, 0);
        }
    }

#pragma unroll
    for (int nt = 0; nt < 8; ++nt)
#pragma unroll
        for (int reg = 0; reg < 4; ++reg) {
            int row = b0 + wave * 16 + quad * 4 + reg;
            out[row * 128 + nt * 16 + m16] = acc[nt][reg];
        }
}

extern "C" void kernel_launch(void* const* d_in, const int* in_sizes, int n_in,
                              void* d_out, int out_size, void* d_ws, size_t ws_size,
                              hipStream_t stream) {
    const float* feat  = (const float*)d_in[0];
    const float* w1    = (const float*)d_in[1];
    const float* w2    = (const float*)d_in[2];
    const int*   nbr   = (const int*)d_in[3];
    const int*   nodes = (const int*)d_in[4];
    float* out = (float*)d_out;

    char* ws = (char*)d_ws;
    unsigned short* fb  = (unsigned short*)ws;                       // N*128 bf16 = 25.6 MB
    unsigned char*  f8s = (unsigned char*)(ws + 25600000);           // 4 x N*32 fp8 = 12.8 MB
    unsigned short* agg = (unsigned short*)(ws + 38400000);          // N*128 bf16 = 25.6 MB
    unsigned short* h1  = (unsigned short*)(ws + 64000000);          // N*128 bf16 = 25.6 MB
    unsigned short* w1T = (unsigned short*)(ws + 89600000);          // 64 KB
    unsigned short* w2T = (unsigned short*)(ws + 89665536);          // 64 KB

    prep<<<6266, 256, 0, stream>>>(feat, w1, w2, fb, f8s, w1T, w2T);
    k1_agg<<<6256, 256, 0, stream>>>(f8s, nbr, agg);
    g1<<<(N_NODES + 127) / 128, 256, 0, stream>>>(fb, agg, w1T, h1);
    g2_fused<<<B_NODES / 64, 256, 0, stream>>>(h1, w2T, nbr, nodes, out);
}

// Round 8
// 165.872 us; speedup vs baseline: 1.1691x; 1.0439x over previous
//
#include <hip/hip_runtime.h>

// GraphSage on MI355X — round 8.
//   prep  : feat fp32 -> fb bf16 (GEMM self operand) + f8 fp8 e4m3 [N][128B] (gather src)
//           + w1,w2 -> w1T,w2T bf16 [n][k]
//   k1_agg: async-DMA gather: each lane issues 16 global_load_lds (16 B each, zero VGPR
//           cost -> full MLP; rounds 1-7 showed the allocator caps register-destined
//           gathers at ~4 outstanding). One barrier drains vmcnt, then convert+mean
//           from wave-private LDS. 8 lanes/node = full 128-B row, no line waste.
//   g1    : h1 = [fb | agg] @ w1T.  m97-style BK=32 double-buffered global_load_lds.
//   g2    : out = [h1[node] | mean h1[nbr]] @ w2T  (fused, 64 rows/block)

#define N_NODES 100000
#define DEG     16
#define FDIM    128
#define HDIM    128
#define B_NODES 8192

typedef __attribute__((ext_vector_type(8))) short bf16x8;
typedef __attribute__((ext_vector_type(8))) unsigned short u16x8;
typedef __attribute__((ext_vector_type(4))) float f32x4;
typedef __attribute__((ext_vector_type(2))) float f32x2;

static __device__ __forceinline__ unsigned short f2bf(float f) {
    union { float f; unsigned u; } v; v.f = f;
    unsigned r = v.u + 0x7fff + ((v.u >> 16) & 1);   // RNE
    return (unsigned short)(r >> 16);
}
static __device__ __forceinline__ float bf2f(unsigned short b) {
    union { unsigned u; float f; } v; v.u = ((unsigned)b) << 16;
    return v.f;
}

// blocks 0..6249: cast feat -> fb (bf16) + f8 (fp8). blocks 6250..6265: w1/w2 transpose.
__global__ __launch_bounds__(256)
void prep(const float* __restrict__ feat, const float* __restrict__ w1,
          const float* __restrict__ w2, unsigned short* __restrict__ fb,
          unsigned char* __restrict__ f8,
          unsigned short* __restrict__ w1T, unsigned short* __restrict__ w2T) {
    if (blockIdx.x < 6250) {
        long e = ((long)blockIdx.x * 256 + threadIdx.x) * 8;   // 6250*256*8 = 12.8M exact
        float4 v0 = *(const float4*)(feat + e);
        float4 v1 = *(const float4*)(feat + e + 4);
        u16x8 ob;
        ob[0] = f2bf(v0.x); ob[1] = f2bf(v0.y); ob[2] = f2bf(v0.z); ob[3] = f2bf(v0.w);
        ob[4] = f2bf(v1.x); ob[5] = f2bf(v1.y); ob[6] = f2bf(v1.z); ob[7] = f2bf(v1.w);
        *(u16x8*)(fb + e) = ob;
        int p0 = 0, p1 = 0;
        p0 = __builtin_amdgcn_cvt_pk_fp8_f32(v0.x, v0.y, p0, false);
        p0 = __builtin_amdgcn_cvt_pk_fp8_f32(v0.z, v0.w, p0, true);
        p1 = __builtin_amdgcn_cvt_pk_fp8_f32(v1.x, v1.y, p1, false);
        p1 = __builtin_amdgcn_cvt_pk_fp8_f32(v1.z, v1.w, p1, true);
        uint2 o8; o8.x = (unsigned)p0; o8.y = (unsigned)p1;
        *(uint2*)(f8 + e) = o8;
    } else {
        int bid = blockIdx.x - 6250;
        const float* w = (bid < 8) ? w1 : w2;
        unsigned short* wT = (bid < 8) ? w1T : w2T;
        int kb = (bid & 7) * 32;
        int n = threadIdx.x & 127, dk = threadIdx.x >> 7;
#pragma unroll
        for (int i = 0; i < 16; ++i) {
            int k = kb + dk * 16 + i;
            wT[n * 256 + k] = f2bf(w[k * 128 + n]);   // read coalesced over n
        }
    }
}

// Async-DMA gather. 32 nodes/block (8 lanes x 16 B = full 128-B fp8 row per node).
// 16 gathers/lane issued via global_load_lds (no VGPR dest -> all in flight), one
// barrier (drains vmcnt), then wave-private LDS readback + fp8->f32 mean.
__global__ __launch_bounds__(256)
void k1_agg(const unsigned char* __restrict__ f8, const int* __restrict__ nbr,
            unsigned short* __restrict__ agg) {
    __shared__ unsigned char L[4][16][1024];   // 64 KB: [wave][d][lane*16B]
    const int t = threadIdx.x, wave = t >> 6, lane = t & 63;
    const int node = blockIdx.x * 32 + (t >> 3);   // 3125*32 = 100000 exact
    const int sub = t & 7;
    const int* idx = nbr + node * DEG;
    int4 i0 = *(const int4*)(idx);
    int4 i1 = *(const int4*)(idx + 4);
    int4 i2 = *(const int4*)(idx + 8);
    int4 i3 = *(const int4*)(idx + 12);
    const int id[16] = {i0.x, i0.y, i0.z, i0.w, i1.x, i1.y, i1.z, i1.w,
                        i2.x, i2.y, i2.z, i2.w, i3.x, i3.y, i3.z, i3.w};
#pragma unroll
    for (int d = 0; d < DEG; ++d) {
        const unsigned char* src = f8 + (long)id[d] * 128 + sub * 16;
        __builtin_amdgcn_global_load_lds(
            (const __attribute__((address_space(1))) unsigned int*)src,
            (__attribute__((address_space(3))) unsigned int*)(&L[wave][d][lane * 16]),
            16, 0, 0);
    }
    __syncthreads();   // compiler emits s_waitcnt vmcnt(0) before s_barrier -> DMA landed

    float s[16];
#pragma unroll
    for (int j = 0; j < 16; ++j) s[j] = 0.f;
#pragma unroll
    for (int d = 0; d < DEG; ++d) {
        uint4 v = *(const uint4*)(&L[wave][d][lane * 16]);
        f32x2 c;
        c = __builtin_amdgcn_cvt_pk_f32_fp8((int)v.x, false); s[0]  += c[0]; s[1]  += c[1];
        c = __builtin_amdgcn_cvt_pk_f32_fp8((int)v.x, true);  s[2]  += c[0]; s[3]  += c[1];
        c = __builtin_amdgcn_cvt_pk_f32_fp8((int)v.y, false); s[4]  += c[0]; s[5]  += c[1];
        c = __builtin_amdgcn_cvt_pk_f32_fp8((int)v.y, true);  s[6]  += c[0]; s[7]  += c[1];
        c = __builtin_amdgcn_cvt_pk_f32_fp8((int)v.z, false); s[8]  += c[0]; s[9]  += c[1];
        c = __builtin_amdgcn_cvt_pk_f32_fp8((int)v.z, true);  s[10] += c[0]; s[11] += c[1];
        c = __builtin_amdgcn_cvt_pk_f32_fp8((int)v.w, false); s[12] += c[0]; s[13] += c[1];
        c = __builtin_amdgcn_cvt_pk_f32_fp8((int)v.w, true);  s[14] += c[0]; s[15] += c[1];
    }
    u16x8 o0, o1;
#pragma unroll
    for (int j = 0; j < 8; ++j) {
        o0[j] = f2bf(s[j] * 0.0625f);
        o1[j] = f2bf(s[8 + j] * 0.0625f);
    }
    unsigned short* dst = agg + (long)node * 128 + sub * 16;
    *(u16x8*)dst = o0;
    *(u16x8*)(dst + 8) = o1;
}

// Stage one K-chunk (A rows + W rows, 8 KB each) into LDS buf via global_load_lds.
#define STAGE(KC, BUF)                                                                        \
    do {                                                                                      \
        const unsigned short* s0_ = ((KC) < 4) ? (fb + (KC) * 32) : (agg + ((KC) - 4) * 32);  \
        _Pragma("unroll")                                                                     \
        for (int j_ = 0; j_ < 2; ++j_) {                                                      \
            long grow_ = row0 + (t >> 2) + j_ * 64;                                           \
            const unsigned short* ga_ = s0_ + grow_ * 128 + (t & 3) * 8;                      \
            __builtin_amdgcn_global_load_lds(                                                 \
                (const __attribute__((address_space(1))) unsigned int*)ga_,                   \
                (__attribute__((address_space(3))) unsigned int*)                             \
                    (&AsS[(BUF) * 4096 + wave * 512 + j_ * 2048 + lane * 8]), 16, 0, 0);      \
            const unsigned short* gw_ = w1T + ((t >> 2) + j_ * 64) * 256 + (KC) * 32 + (t & 3) * 8; \
            __builtin_amdgcn_global_load_lds(                                                 \
                (const __attribute__((address_space(1))) unsigned int*)gw_,                   \
                (__attribute__((address_space(3))) unsigned int*)                             \
                    (&WsS[(BUF) * 4096 + wave * 512 + j_ * 2048 + lane * 8]), 16, 0, 0);      \
        }                                                                                     \
    } while (0)

// GEMM: h1[N,128] = [fb | agg] @ w1T. 128 rows/block, BK=32, double-buffered async LDS.
__global__ __launch_bounds__(256, 2)
void g1(const unsigned short* __restrict__ fb, const unsigned short* __restrict__ agg,
        const unsigned short* __restrict__ w1T, unsigned short* __restrict__ h1) {
    __shared__ unsigned short AsS[2 * 4096];   // 2 x 128 rows x 32 k (8 KB each)
    __shared__ unsigned short WsS[2 * 4096];
    const int t = threadIdx.x, wave = t >> 6, lane = t & 63;
    const int m16 = lane & 15, quad = lane >> 4;
    const long row0 = (long)blockIdx.x * 128;

    f32x4 acc[2][8] = {};
    STAGE(0, 0);
#pragma unroll
    for (int kc = 0; kc < 8; ++kc) {
        __syncthreads();                       // drains vmcnt -> staging of kc complete
        if (kc < 7) {
            switch (kc + 1) {
                case 1: STAGE(1, 1); break;
                case 2: STAGE(2, 0); break;
                case 3: STAGE(3, 1); break;
                case 4: STAGE(4, 0); break;
                case 5: STAGE(5, 1); break;
                case 6: STAGE(6, 0); break;
                case 7: STAGE(7, 1); break;
            }
        }
        const unsigned short* Ab = &AsS[(kc & 1) * 4096];
        const unsigned short* Wb = &WsS[(kc & 1) * 4096];
        bf16x8 a0 = *(const bf16x8*)(Ab + (wave * 32 + m16) * 32 + quad * 8);
        bf16x8 a1 = *(const bf16x8*)(Ab + (wave * 32 + 16 + m16) * 32 + quad * 8);
#pragma unroll
        for (int nt = 0; nt < 8; ++nt) {
            bf16x8 bv = *(const bf16x8*)(Wb + (nt * 16 + m16) * 32 + quad * 8);
            acc[0][nt] = __builtin_amdgcn_mfma_f32_16x16x32_bf16(a0, bv, acc[0][nt], 0, 0, 0);
            acc[1][nt] = __builtin_amdgcn_mfma_f32_16x16x32_bf16(a1, bv, acc[1][nt], 0, 0, 0);
        }
    }

    // C layout: row = quad*4 + reg, col = nt*16 + m16
#pragma unroll
    for (int mt = 0; mt < 2; ++mt)
#pragma unroll
        for (int reg = 0; reg < 4; ++reg) {
            long grow = row0 + wave * 32 + mt * 16 + quad * 4 + reg;
            if (grow >= N_NODES) continue;
#pragma unroll
            for (int nt = 0; nt < 8; ++nt)
                h1[grow * HDIM + nt * 16 + m16] = f2bf(acc[mt][nt][reg]);
        }
}

// Layer 2 fused: 64 batch rows per 256-thread block. 128 blocks exact.
__global__ __launch_bounds__(256)
void g2_fused(const unsigned short* __restrict__ h1, const unsigned short* __restrict__ w2T,
              const int* __restrict__ nbr, const int* __restrict__ nodes,
              float* __restrict__ out) {
    __shared__ unsigned short X2[64][264];
    const int t = threadIdx.x, wave = t >> 6, lane = t & 63;
    const int m16 = lane & 15, quad = lane >> 4;
    const int b0 = blockIdx.x * 64;
    const int colb = m16 * 8;

    for (int g = 0; g < 4; ++g) {
        int Ln = wave * 16 + g * 4 + quad;
        int node = nodes[b0 + Ln];
        *(u16x8*)(&X2[Ln][colb]) = *(const u16x8*)(h1 + node * HDIM + colb);
        const int* idx = nbr + node * DEG;
        float s[8] = {0.f, 0.f, 0.f, 0.f, 0.f, 0.f, 0.f, 0.f};
#pragma unroll
        for (int d = 0; d < DEG; ++d) {
            int nb = idx[d];
            u16x8 v = *(const u16x8*)(h1 + nb * HDIM + colb);
#pragma unroll
            for (int j = 0; j < 8; ++j) s[j] += bf2f(v[j]);
        }
        u16x8 o;
#pragma unroll
        for (int j = 0; j < 8; ++j) o[j] = f2bf(s[j] * 0.0625f);
        *(u16x8*)(&X2[Ln][128 + colb]) = o;
    }
    __syncthreads();

    f32x4 acc[8] = {};
#pragma unroll
    for (int kc = 0; kc < 8; ++kc) {
        bf16x8 a = *(const bf16x8*)(&X2[wave * 16 + m16][kc * 32 + quad * 8]);
#pragma unroll
        for (int nt = 0; nt < 8; ++nt) {
            bf16x8 b = *(const bf16x8*)(w2T + (nt * 16 + m16) * 256 + kc * 32 + quad * 8);
            acc[nt] = __builtin_amdgcn_mfma_f32_16x16x32_bf16(a, b, acc[nt], 0, 0, 0);
        }
    }

#pragma unroll
    for (int nt = 0; nt < 8; ++nt)
#pragma unroll
        for (int reg = 0; reg < 4; ++reg) {
            int row = b0 + wave * 16 + quad * 4 + reg;
            out[row * 128 + nt * 16 + m16] = acc[nt][reg];
        }
}

extern "C" void kernel_launch(void* const* d_in, const int* in_sizes, int n_in,
                              void* d_out, int out_size, void* d_ws, size_t ws_size,
                              hipStream_t stream) {
    const float* feat  = (const float*)d_in[0];
    const float* w1    = (const float*)d_in[1];
    const float* w2    = (const float*)d_in[2];
    const int*   nbr   = (const int*)d_in[3];
    const int*   nodes = (const int*)d_in[4];
    float* out = (float*)d_out;

    char* ws = (char*)d_ws;
    unsigned short* fb  = (unsigned short*)ws;                       // N*128 bf16 = 25.6 MB
    unsigned char*  f8  = (unsigned char*)(ws + 25600000);           // N*128 fp8  = 12.8 MB
    unsigned short* agg = (unsigned short*)(ws + 38400000);          // N*128 bf16 = 25.6 MB
    unsigned short* h1  = (unsigned short*)(ws + 64000000);          // N*128 bf16 = 25.6 MB
    unsigned short* w1T = (unsigned short*)(ws + 89600000);          // 64 KB
    unsigned short* w2T = (unsigned short*)(ws + 89665536);          // 64 KB

    prep<<<6266, 256, 0, stream>>>(feat, w1, w2, fb, f8, w1T, w2T);
    k1_agg<<<3125, 256, 0, stream>>>(f8, nbr, agg);
    g1<<<(N_NODES + 127) / 128, 256, 0, stream>>>(fb, agg, w1T, h1);
    g2_fused<<<B_NODES / 64, 256, 0, stream>>>(h1, w2T, nbr, nodes, out);
}

// Round 9
// 165.171 us; speedup vs baseline: 1.1741x; 1.0042x over previous
//
#include <hip/hip_runtime.h>

// GraphSage on MI355X — round 9.
//   prep  : feat fp32 -> fb bf16 (GEMM self operand) + f8 fp8 e4m3 [N][128B] (gather src)
//           + w1,w2 -> w1T,w2T bf16 [n][k]
//   k1_agg: async-DMA gather, 1-wave blocks (no barriers): 16 global_load_lds per lane
//           (zero VGPR cost -> full MLP), raw wave-local s_waitcnt vmcnt(0), convert
//           from wave-private LDS with packed f32x2 adds. 16 KB LDS -> 10 blocks/CU.
//   g1    : h1 = [fb | agg] @ w1T.  m97-style BK=32 double-buffered global_load_lds,
//           4 blocks/CU (staging-latency-bound; MFMA is ~6% of cycles).
//   g2    : out = [h1[node] | mean h1[nbr]] @ w2T  (fused, 64 rows/block)

#define N_NODES 100000
#define DEG     16
#define FDIM    128
#define HDIM    128
#define B_NODES 8192

typedef __attribute__((ext_vector_type(8))) short bf16x8;
typedef __attribute__((ext_vector_type(8))) unsigned short u16x8;
typedef __attribute__((ext_vector_type(4))) float f32x4;
typedef __attribute__((ext_vector_type(2))) float f32x2;

static __device__ __forceinline__ unsigned short f2bf(float f) {
    union { float f; unsigned u; } v; v.f = f;
    unsigned r = v.u + 0x7fff + ((v.u >> 16) & 1);   // RNE
    return (unsigned short)(r >> 16);
}
static __device__ __forceinline__ float bf2f(unsigned short b) {
    union { unsigned u; float f; } v; v.u = ((unsigned)b) << 16;
    return v.f;
}

// blocks 0..6249: cast feat -> fb (bf16) + f8 (fp8). blocks 6250..6265: w1/w2 transpose.
__global__ __launch_bounds__(256)
void prep(const float* __restrict__ feat, const float* __restrict__ w1,
          const float* __restrict__ w2, unsigned short* __restrict__ fb,
          unsigned char* __restrict__ f8,
          unsigned short* __restrict__ w1T, unsigned short* __restrict__ w2T) {
    if (blockIdx.x < 6250) {
        long e = ((long)blockIdx.x * 256 + threadIdx.x) * 8;   // 6250*256*8 = 12.8M exact
        float4 v0 = *(const float4*)(feat + e);
        float4 v1 = *(const float4*)(feat + e + 4);
        u16x8 ob;
        ob[0] = f2bf(v0.x); ob[1] = f2bf(v0.y); ob[2] = f2bf(v0.z); ob[3] = f2bf(v0.w);
        ob[4] = f2bf(v1.x); ob[5] = f2bf(v1.y); ob[6] = f2bf(v1.z); ob[7] = f2bf(v1.w);
        *(u16x8*)(fb + e) = ob;
        int p0 = 0, p1 = 0;
        p0 = __builtin_amdgcn_cvt_pk_fp8_f32(v0.x, v0.y, p0, false);
        p0 = __builtin_amdgcn_cvt_pk_fp8_f32(v0.z, v0.w, p0, true);
        p1 = __builtin_amdgcn_cvt_pk_fp8_f32(v1.x, v1.y, p1, false);
        p1 = __builtin_amdgcn_cvt_pk_fp8_f32(v1.z, v1.w, p1, true);
        uint2 o8; o8.x = (unsigned)p0; o8.y = (unsigned)p1;
        *(uint2*)(f8 + e) = o8;
    } else {
        int bid = blockIdx.x - 6250;
        const float* w = (bid < 8) ? w1 : w2;
        unsigned short* wT = (bid < 8) ? w1T : w2T;
        int kb = (bid & 7) * 32;
        int n = threadIdx.x & 127, dk = threadIdx.x >> 7;
#pragma unroll
        for (int i = 0; i < 16; ++i) {
            int k = kb + dk * 16 + i;
            wT[n * 256 + k] = f2bf(w[k * 128 + n]);   // read coalesced over n
        }
    }
}

// Async-DMA gather, 1-wave blocks. 8 nodes/block (8 lanes x 16 B = full 128-B row).
// No __syncthreads anywhere: the only wait is this wave's own vmcnt(0).
__global__ __launch_bounds__(64)
void k1_agg(const unsigned char* __restrict__ f8, const int* __restrict__ nbr,
            unsigned short* __restrict__ agg) {
    __shared__ unsigned char L[16][1024];   // 16 KB: [d][lane*16B] -> 10 blocks/CU
    const int lane = threadIdx.x;
    const int node = blockIdx.x * 8 + (lane >> 3);   // 12500*8 = 100000 exact
    const int sub = lane & 7;
    const int* idx = nbr + node * DEG;
    int4 i0 = *(const int4*)(idx);
    int4 i1 = *(const int4*)(idx + 4);
    int4 i2 = *(const int4*)(idx + 8);
    int4 i3 = *(const int4*)(idx + 12);
    const int id[16] = {i0.x, i0.y, i0.z, i0.w, i1.x, i1.y, i1.z, i1.w,
                        i2.x, i2.y, i2.z, i2.w, i3.x, i3.y, i3.z, i3.w};
#pragma unroll
    for (int d = 0; d < DEG; ++d) {
        const unsigned char* src = f8 + (long)id[d] * 128 + sub * 16;
        __builtin_amdgcn_global_load_lds(
            (const __attribute__((address_space(1))) unsigned int*)src,
            (__attribute__((address_space(3))) unsigned int*)(&L[d][lane * 16]),
            16, 0, 0);
    }
    asm volatile("s_waitcnt vmcnt(0)" ::: "memory");   // wave-local DMA drain

    f32x2 s2[8];
#pragma unroll
    for (int j = 0; j < 8; ++j) s2[j] = (f32x2){0.f, 0.f};
#pragma unroll
    for (int d = 0; d < DEG; ++d) {
        uint4 v = *(const uint4*)(&L[d][lane * 16]);
        s2[0] += __builtin_amdgcn_cvt_pk_f32_fp8((int)v.x, false);
        s2[1] += __builtin_amdgcn_cvt_pk_f32_fp8((int)v.x, true);
        s2[2] += __builtin_amdgcn_cvt_pk_f32_fp8((int)v.y, false);
        s2[3] += __builtin_amdgcn_cvt_pk_f32_fp8((int)v.y, true);
        s2[4] += __builtin_amdgcn_cvt_pk_f32_fp8((int)v.z, false);
        s2[5] += __builtin_amdgcn_cvt_pk_f32_fp8((int)v.z, true);
        s2[6] += __builtin_amdgcn_cvt_pk_f32_fp8((int)v.w, false);
        s2[7] += __builtin_amdgcn_cvt_pk_f32_fp8((int)v.w, true);
    }
    u16x8 o0, o1;
#pragma unroll
    for (int j = 0; j < 8; ++j) {
        o0[j] = f2bf(s2[j >> 1][j & 1] * 0.0625f);
        o1[j] = f2bf(s2[4 + (j >> 1)][j & 1] * 0.0625f);
    }
    unsigned short* dst = agg + (long)node * 128 + sub * 16;
    *(u16x8*)dst = o0;
    *(u16x8*)(dst + 8) = o1;
}

// Stage one K-chunk (A rows + W rows, 8 KB each) into LDS buf via global_load_lds.
#define STAGE(KC, BUF)                                                                        \
    do {                                                                                      \
        const unsigned short* s0_ = ((KC) < 4) ? (fb + (KC) * 32) : (agg + ((KC) - 4) * 32);  \
        _Pragma("unroll")                                                                     \
        for (int j_ = 0; j_ < 2; ++j_) {                                                      \
            long grow_ = row0 + (t >> 2) + j_ * 64;                                           \
            const unsigned short* ga_ = s0_ + grow_ * 128 + (t & 3) * 8;                      \
            __builtin_amdgcn_global_load_lds(                                                 \
                (const __attribute__((address_space(1))) unsigned int*)ga_,                   \
                (__attribute__((address_space(3))) unsigned int*)                             \
                    (&AsS[(BUF) * 4096 + wave * 512 + j_ * 2048 + lane * 8]), 16, 0, 0);      \
            const unsigned short* gw_ = w1T + ((t >> 2) + j_ * 64) * 256 + (KC) * 32 + (t & 3) * 8; \
            __builtin_amdgcn_global_load_lds(                                                 \
                (const __attribute__((address_space(1))) unsigned int*)gw_,                   \
                (__attribute__((address_space(3))) unsigned int*)                             \
                    (&WsS[(BUF) * 4096 + wave * 512 + j_ * 2048 + lane * 8]), 16, 0, 0);      \
        }                                                                                     \
    } while (0)

// GEMM: h1[N,128] = [fb | agg] @ w1T. 128 rows/block, BK=32, double-buffered async LDS.
// 4 blocks/CU: staging-latency-bound, so TLP is the lever (MFMA ~6% of cycles).
__global__ __launch_bounds__(256, 4)
void g1(const unsigned short* __restrict__ fb, const unsigned short* __restrict__ agg,
        const unsigned short* __restrict__ w1T, unsigned short* __restrict__ h1) {
    __shared__ unsigned short AsS[2 * 4096];   // 2 x 128 rows x 32 k (8 KB each)
    __shared__ unsigned short WsS[2 * 4096];
    const int t = threadIdx.x, wave = t >> 6, lane = t & 63;
    const int m16 = lane & 15, quad = lane >> 4;
    const long row0 = (long)blockIdx.x * 128;

    f32x4 acc[2][8] = {};
    STAGE(0, 0);
#pragma unroll
    for (int kc = 0; kc < 8; ++kc) {
        __syncthreads();                       // drains vmcnt -> staging of kc complete
        if (kc < 7) {
            switch (kc + 1) {
                case 1: STAGE(1, 1); break;
                case 2: STAGE(2, 0); break;
                case 3: STAGE(3, 1); break;
                case 4: STAGE(4, 0); break;
                case 5: STAGE(5, 1); break;
                case 6: STAGE(6, 0); break;
                case 7: STAGE(7, 1); break;
            }
        }
        const unsigned short* Ab = &AsS[(kc & 1) * 4096];
        const unsigned short* Wb = &WsS[(kc & 1) * 4096];
        bf16x8 a0 = *(const bf16x8*)(Ab + (wave * 32 + m16) * 32 + quad * 8);
        bf16x8 a1 = *(const bf16x8*)(Ab + (wave * 32 + 16 + m16) * 32 + quad * 8);
#pragma unroll
        for (int nt = 0; nt < 8; ++nt) {
            bf16x8 bv = *(const bf16x8*)(Wb + (nt * 16 + m16) * 32 + quad * 8);
            acc[0][nt] = __builtin_amdgcn_mfma_f32_16x16x32_bf16(a0, bv, acc[0][nt], 0, 0, 0);
            acc[1][nt] = __builtin_amdgcn_mfma_f32_16x16x32_bf16(a1, bv, acc[1][nt], 0, 0, 0);
        }
    }

    // C layout: row = quad*4 + reg, col = nt*16 + m16
#pragma unroll
    for (int mt = 0; mt < 2; ++mt)
#pragma unroll
        for (int reg = 0; reg < 4; ++reg) {
            long grow = row0 + wave * 32 + mt * 16 + quad * 4 + reg;
            if (grow >= N_NODES) continue;
#pragma unroll
            for (int nt = 0; nt < 8; ++nt)
                h1[grow * HDIM + nt * 16 + m16] = f2bf(acc[mt][nt][reg]);
        }
}

// Layer 2 fused: 64 batch rows per 256-thread block. 128 blocks exact.
__global__ __launch_bounds__(256)
void g2_fused(const unsigned short* __restrict__ h1, const unsigned short* __restrict__ w2T,
              const int* __restrict__ nbr, const int* __restrict__ nodes,
              float* __restrict__ out) {
    __shared__ unsigned short X2[64][264];
    const int t = threadIdx.x, wave = t >> 6, lane = t & 63;
    const int m16 = lane & 15, quad = lane >> 4;
    const int b0 = blockIdx.x * 64;
    const int colb = m16 * 8;

    for (int g = 0; g < 4; ++g) {
        int Ln = wave * 16 + g * 4 + quad;
        int node = nodes[b0 + Ln];
        *(u16x8*)(&X2[Ln][colb]) = *(const u16x8*)(h1 + node * HDIM + colb);
        const int* idx = nbr + node * DEG;
        float s[8] = {0.f, 0.f, 0.f, 0.f, 0.f, 0.f, 0.f, 0.f};
#pragma unroll
        for (int d = 0; d < DEG; ++d) {
            int nb = idx[d];
            u16x8 v = *(const u16x8*)(h1 + nb * HDIM + colb);
#pragma unroll
            for (int j = 0; j < 8; ++j) s[j] += bf2f(v[j]);
        }
        u16x8 o;
#pragma unroll
        for (int j = 0; j < 8; ++j) o[j] = f2bf(s[j] * 0.0625f);
        *(u16x8*)(&X2[Ln][128 + colb]) = o;
    }
    __syncthreads();

    f32x4 acc[8] = {};
#pragma unroll
    for (int kc = 0; kc < 8; ++kc) {
        bf16x8 a = *(const bf16x8*)(&X2[wave * 16 + m16][kc * 32 + quad * 8]);
#pragma unroll
        for (int nt = 0; nt < 8; ++nt) {
            bf16x8 b = *(const bf16x8*)(w2T + (nt * 16 + m16) * 256 + kc * 32 + quad * 8);
            acc[nt] = __builtin_amdgcn_mfma_f32_16x16x32_bf16(a, b, acc[nt], 0, 0, 0);
        }
    }

#pragma unroll
    for (int nt = 0; nt < 8; ++nt)
#pragma unroll
        for (int reg = 0; reg < 4; ++reg) {
            int row = b0 + wave * 16 + quad * 4 + reg;
            out[row * 128 + nt * 16 + m16] = acc[nt][reg];
        }
}

extern "C" void kernel_launch(void* const* d_in, const int* in_sizes, int n_in,
                              void* d_out, int out_size, void* d_ws, size_t ws_size,
                              hipStream_t stream) {
    const float* feat  = (const float*)d_in[0];
    const float* w1    = (const float*)d_in[1];
    const float* w2    = (const float*)d_in[2];
    const int*   nbr   = (const int*)d_in[3];
    const int*   nodes = (const int*)d_in[4];
    float* out = (float*)d_out;

    char* ws = (char*)d_ws;
    unsigned short* fb  = (unsigned short*)ws;                       // N*128 bf16 = 25.6 MB
    unsigned char*  f8  = (unsigned char*)(ws + 25600000);           // N*128 fp8  = 12.8 MB
    unsigned short* agg = (unsigned short*)(ws + 38400000);          // N*128 bf16 = 25.6 MB
    unsigned short* h1  = (unsigned short*)(ws + 64000000);          // N*128 bf16 = 25.6 MB
    unsigned short* w1T = (unsigned short*)(ws + 89600000);          // 64 KB
    unsigned short* w2T = (unsigned short*)(ws + 89665536);          // 64 KB

    prep<<<6266, 256, 0, stream>>>(feat, w1, w2, fb, f8, w1T, w2T);
    k1_agg<<<12500, 64, 0, stream>>>(f8, nbr, agg);
    g1<<<(N_NODES + 127) / 128, 256, 0, stream>>>(fb, agg, w1T, h1);
    g2_fused<<<B_NODES / 64, 256, 0, stream>>>(h1, w2T, nbr, nodes, out);
}